// Round 11
// baseline (22.502 us; speedup 1.0000x reference)
//
#include <hip/hip_runtime.h>
#include <cmath>

// Cox partial likelihood (Breslow) loss, N=16384.
// denom[i] = sum_j [t_j >= t_i] * exp(est_j)
// loss = sum_i ev_i * (log(denom[i]) - est[i]) / max(sum ev, 1)
//
// R11 = R10 with CS 512->256: K1 rank work halves and spreads over 64
// blocks (float-compare + index tiebreak ranks, proven in R8). K2 stages
// the full sorted table (64KB) in LDS, runs 64 depth-9 searches per query
// round-interleaved (16-wide ILP). K3 finalizes. Deterministic: unique
// ranks, fixed reduction trees, no float atomics, no device fences.

#define CS    256                 // chunk size (= K1 block size)
#define NCH   64                  // chunks (n / CS)
#define SUBS  4                   // sub-threads per query in K2
#define CHPS  (NCH / SUBS)        // 16 chunks per sub-thread
#define QPB   64                  // queries per K2 block
#define K2THR (QPB * SUBS)        // 256 threads
#define K2NB  256                 // n / QPB

// ---------------------------------------------------------------------------
// K1: per-chunk rank sort + suffix sums of e = exp(est) + orig-index perm.
__global__ __launch_bounds__(CS)
void cox_sort(const float2* __restrict__ tg,
              const float* __restrict__ est,
              float* __restrict__ ts,    // [n] sorted t (per chunk)
              float* __restrict__ ss,    // [n] suffix sums of e (per chunk)
              int* __restrict__ so) {    // [n] orig index of sorted elem
    __shared__ float st[CS];                  // raw t
    __shared__ float srt[CS];                 // sorted t
    __shared__ float sea[CS], seb[CS];        // ping-pong scan
    __shared__ int   sso[CS];                 // orig index

    const int tid = threadIdx.x;
    const int j   = blockIdx.x * CS + tid;

    const float tj = tg[j].x;
    const float ej = expf(est[j]);
    st[tid] = tj;
    __syncthreads();

    // rank = #{k : (t_k, k) < (t_j, j)} -- unique -> permutation
    int rank = 0;
    const float4* t4 = (const float4*)st;
    #pragma unroll 8
    for (int k4 = 0; k4 < CS / 4; ++k4) {
        float4 p = t4[k4];
        const int k = k4 * 4;
        rank += (p.x < tj) || (p.x == tj && (k + 0) < tid);
        rank += (p.y < tj) || (p.y == tj && (k + 1) < tid);
        rank += (p.z < tj) || (p.z == tj && (k + 2) < tid);
        rank += (p.w < tj) || (p.w == tj && (k + 3) < tid);
    }

    srt[rank] = tj;
    sea[rank] = ej;
    sso[rank] = j;
    __syncthreads();

    // inclusive suffix scan, ping-pong (1 barrier/round, deterministic)
    float* a = sea;
    float* b = seb;
    #pragma unroll
    for (int off = 1; off < CS; off <<= 1) {
        b[tid] = a[tid] + ((tid + off < CS) ? a[tid + off] : 0.f);
        __syncthreads();
        float* tmp = a; a = b; b = tmp;
    }

    ts[j] = srt[tid];
    ss[j] = a[tid];
    so[j] = sso[tid];
}

// ---------------------------------------------------------------------------
// K2: full sorted-t table in LDS; 16 chunk-searches per sub, round-
// interleaved for ILP. Block = 256 thr = 64 queries x 4 subs.
__global__ __launch_bounds__(K2THR)
void cox_search(const float2* __restrict__ tg,
                const float* __restrict__ est,
                const float* __restrict__ ts,
                const float* __restrict__ ss,
                const int* __restrict__ so,
                float* __restrict__ ploss,
                float* __restrict__ pev) {
    __shared__ float lts[NCH * CS];             // 64 KB: whole sorted table
    __shared__ float sl[K2THR / 64], sv[K2THR / 64];

    const int tid = threadIdx.x;
    const int sub = tid & (SUBS - 1);
    const int qid = blockIdx.x * QPB + (tid >> 2);  // per-chunk sorted pos

    // ---- stage the full table (coalesced float4) ----
    {
        float4* l4 = (float4*)lts;
        const float4* g4 = (const float4*)ts;
        #pragma unroll
        for (int k = 0; k < (NCH * CS / 4) / K2THR; ++k)
            l4[tid + k * K2THR] = g4[tid + k * K2THR];
    }
    __syncthreads();

    const float ti = lts[qid];

    // ---- 16 branchless lower_bounds, round-interleaved (16-wide ILP) ----
    int pos[CHPS];
    #pragma unroll
    for (int c = 0; c < CHPS; ++c) pos[c] = 0;

    #pragma unroll
    for (int s = CS / 2; s >= 1; s >>= 1) {
        float v[CHPS];
        #pragma unroll
        for (int c = 0; c < CHPS; ++c)
            v[c] = lts[((sub * CHPS + c) << 8) + pos[c] + s - 1];
        #pragma unroll
        for (int c = 0; c < CHPS; ++c)
            pos[c] += (v[c] < ti) ? s : 0;
    }
    {   // final refinement round: pos in [0,256]
        float v[CHPS];
        #pragma unroll
        for (int c = 0; c < CHPS; ++c)
            v[c] = lts[((sub * CHPS + c) << 8) + pos[c]];
        #pragma unroll
        for (int c = 0; c < CHPS; ++c)
            pos[c] += (v[c] < ti) ? 1 : 0;
    }

    // ---- gather suffix values (16 independent loads) ----
    float d = 0.f;
    #pragma unroll
    for (int c = 0; c < CHPS; ++c)
        d += (pos[c] < CS) ? ss[((sub * CHPS + c) << 8) + pos[c]] : 0.f;

    // combine 4 subs (fixed tree -> deterministic)
    d += __shfl_down(d, 2, 4);
    d += __shfl_down(d, 1, 4);

    float contrib = 0.f, ev = 0.f;
    if (sub == 0) {
        const int io = so[qid];
        ev      = (tg[io].y != 0.f) ? 1.f : 0.f;
        contrib = ev * (logf(d) - est[io]);
    }
    #pragma unroll
    for (int off = 32; off >= 4; off >>= 1) {
        contrib += __shfl_down(contrib, off, 64);
        ev      += __shfl_down(ev, off, 64);
    }
    if ((tid & 63) == 0) { sl[tid >> 6] = contrib; sv[tid >> 6] = ev; }
    __syncthreads();
    if (tid == 0) {
        float l = 0.f, v = 0.f;
        #pragma unroll
        for (int w = 0; w < K2THR / 64; ++w) { l += sl[w]; v += sv[w]; }
        ploss[blockIdx.x] = l;
        pev[blockIdx.x]   = v;
    }
}

// ---------------------------------------------------------------------------
// K3: final reduction of block partials -> scalar loss.
__global__ void cox_finalize(const float* __restrict__ ploss,
                             const float* __restrict__ pev,
                             float* __restrict__ out,
                             int nblocks) {
    const int tid = threadIdx.x;  // one wave
    float l = 0.f, v = 0.f;
    for (int k = tid; k < nblocks; k += 64) {
        l += ploss[k];
        v += pev[k];
    }
    #pragma unroll
    for (int off = 32; off > 0; off >>= 1) {
        l += __shfl_down(l, off, 64);
        v += __shfl_down(v, off, 64);
    }
    if (tid == 0) out[0] = l / fmaxf(v, 1.f);
}

// ---------------------------------------------------------------------------
extern "C" void kernel_launch(void* const* d_in, const int* in_sizes, int n_in,
                              void* d_out, int out_size, void* d_ws, size_t ws_size,
                              hipStream_t stream) {
    const float*  est = (const float*)d_in[0];
    const float2* tg  = (const float2*)d_in[1];   // target[N][2] = (t, event)
    float*        out = (float*)d_out;

    const int n = in_sizes[0];                    // 16384

    float* ws    = (float*)d_ws;
    float* ts    = ws;                            // [n]
    float* ss    = ws + n;                        // [n]
    int*   so    = (int*)(ws + 2 * n);            // [n]
    float* ploss = ws + 3 * n;                    // [K2NB]
    float* pev   = ploss + K2NB;                  // [K2NB]

    cox_sort<<<n / CS, CS, 0, stream>>>(tg, est, ts, ss, so);
    cox_search<<<K2NB, K2THR, 0, stream>>>(tg, est, ts, ss, so, ploss, pev);
    cox_finalize<<<1, 64, 0, stream>>>(ploss, pev, out, K2NB);
}

// Round 12
// 20.837 us; speedup vs baseline: 1.0799x; 1.0799x over previous
//
#include <hip/hip_runtime.h>
#include <cmath>

// Cox partial likelihood (Breslow) loss, N=16384.
// denom[i] = sum_j [t_j >= t_i] * exp(est_j)
// loss = sum_i ev_i * (log(denom[i]) - est[i]) / max(sum ev, 1)
//
// R12 = R10 (CS=512, LDS-staged round-interleaved searches) + PADDED LDS
// layout (stride 513, odd -> bank = (chunk+pos)%32) to kill the measured
// 781K bank conflicts (R11 counter: stride 512/256 ≡ 0 mod 32 banks made
// bank depend on pos only -> all chunks collided).
// Deterministic: unique sort keys, fixed reduction trees, no float atomics,
// no device fences (R5/R8 lessons).

#define CSZ   512                 // chunk size (= K1 block size)
#define NCH   32                  // chunks (n / CSZ)
#define LSTR  513                 // padded LDS stride (odd -> banks spread)
#define SUBS  4                   // sub-threads per query in K2
#define CHPS  (NCH / SUBS)        // 8 chunks per sub-thread
#define QPB   64                  // queries per K2 block
#define K2THR (QPB * SUBS)        // 256 threads
#define K2NB  256                 // n / QPB

// ---------------------------------------------------------------------------
// K1: per-chunk rank sort + suffix sums of e = exp(est) + orig-index perm.
__global__ __launch_bounds__(CSZ)
void cox_sort(const float2* __restrict__ tg,
              const float* __restrict__ est,
              float* __restrict__ ts,    // [n] sorted t (per chunk)
              float* __restrict__ ss,    // [n] suffix sums of e (per chunk)
              int* __restrict__ so) {    // [n] orig index of sorted elem
    __shared__ unsigned long long skey[CSZ];   // 4 KB
    __shared__ float sst[CSZ];                 // 2 KB
    __shared__ float sea[CSZ], seb[CSZ];       // 4 KB (ping-pong scan)
    __shared__ int   sso[CSZ];                 // 2 KB

    const int tid = threadIdx.x;
    const int j   = blockIdx.x * CSZ + tid;

    const float tj = tg[j].x;
    const float ej = expf(est[j]);
    const unsigned long long key =
        ((unsigned long long)__float_as_uint(tj) << 32) | (unsigned)tid;
    skey[tid] = key;
    __syncthreads();

    // rank = #{k : key_k < key}  (keys unique -> rank is a permutation)
    int rank = 0;
    const ulonglong2* k2 = (const ulonglong2*)skey;
    #pragma unroll 8
    for (int k = 0; k < CSZ / 2; ++k) {
        ulonglong2 p = k2[k];
        rank += (p.x < key) ? 1 : 0;
        rank += (p.y < key) ? 1 : 0;
    }

    sst[rank] = tj;
    sea[rank] = ej;
    sso[rank] = j;
    __syncthreads();

    // inclusive suffix scan, ping-pong (1 barrier/round, deterministic)
    float* a = sea;
    float* b = seb;
    #pragma unroll
    for (int off = 1; off < CSZ; off <<= 1) {
        b[tid] = a[tid] + ((tid + off < CSZ) ? a[tid + off] : 0.f);
        __syncthreads();
        float* tmp = a; a = b; b = tmp;
    }

    ts[j] = sst[tid];
    ss[j] = a[tid];
    so[j] = sso[tid];
}

// ---------------------------------------------------------------------------
// K2: full sorted-t table in LDS at PADDED stride 513; 8 chunk-searches per
// sub, round-interleaved for ILP. Block = 256 thr = 64 queries x 4 subs.
__global__ __launch_bounds__(K2THR)
void cox_search(const float2* __restrict__ tg,
                const float* __restrict__ est,
                const float* __restrict__ ts,
                const float* __restrict__ ss,
                const int* __restrict__ so,
                float* __restrict__ ploss,
                float* __restrict__ pev) {
    __shared__ float lts[NCH * LSTR];           // ~64.1 KB padded table
    __shared__ float sl[K2THR / 64], sv[K2THR / 64];

    const int tid = threadIdx.x;
    const int sub = tid & (SUBS - 1);
    const int qid = blockIdx.x * QPB + (tid >> 2);  // per-chunk sorted pos

    // ---- stage the table: float4 global reads, 4 scalar LDS writes ----
    {
        const float4* g4 = (const float4*)ts;
        #pragma unroll
        for (int k = 0; k < (NCH * CSZ / 4) / K2THR; ++k) {
            const int idx4 = tid + k * K2THR;       // float4 index
            float4 v = g4[idx4];
            const int c   = idx4 >> 7;              // chunk (512/4=128 f4)
            const int pos = (idx4 & 127) << 2;      // float offset in chunk
            const int b   = c * LSTR + pos;
            lts[b + 0] = v.x;
            lts[b + 1] = v.y;
            lts[b + 2] = v.z;
            lts[b + 3] = v.w;
        }
    }
    __syncthreads();

    const float ti = lts[(qid >> 9) * LSTR + (qid & 511)];

    // ---- 8 branchless lower_bounds, round-interleaved (8-wide ILP) ----
    int base[CHPS];
    int pos[CHPS];
    #pragma unroll
    for (int c = 0; c < CHPS; ++c) {
        base[c] = (sub * CHPS + c) * LSTR;
        pos[c]  = 0;
    }

    #pragma unroll
    for (int s = CSZ / 2; s >= 1; s >>= 1) {
        float v[CHPS];
        #pragma unroll
        for (int c = 0; c < CHPS; ++c)
            v[c] = lts[base[c] + pos[c] + s - 1];
        #pragma unroll
        for (int c = 0; c < CHPS; ++c)
            pos[c] += (v[c] < ti) ? s : 0;
    }
    {   // final refinement round: pos in [0,512]
        float v[CHPS];
        #pragma unroll
        for (int c = 0; c < CHPS; ++c)
            v[c] = lts[base[c] + pos[c]];
        #pragma unroll
        for (int c = 0; c < CHPS; ++c)
            pos[c] += (v[c] < ti) ? 1 : 0;
    }

    // ---- gather suffix values (8 independent L2 loads, unpadded ss) ----
    float d = 0.f;
    #pragma unroll
    for (int c = 0; c < CHPS; ++c)
        d += (pos[c] < CSZ) ? ss[((sub * CHPS + c) << 9) + pos[c]] : 0.f;

    // combine 4 subs (fixed tree -> deterministic)
    d += __shfl_down(d, 2, 4);
    d += __shfl_down(d, 1, 4);

    float contrib = 0.f, ev = 0.f;
    if (sub == 0) {
        const int io = so[qid];
        ev      = (tg[io].y != 0.f) ? 1.f : 0.f;
        contrib = ev * (logf(d) - est[io]);
    }
    #pragma unroll
    for (int off = 32; off >= 4; off >>= 1) {
        contrib += __shfl_down(contrib, off, 64);
        ev      += __shfl_down(ev, off, 64);
    }
    if ((tid & 63) == 0) { sl[tid >> 6] = contrib; sv[tid >> 6] = ev; }
    __syncthreads();
    if (tid == 0) {
        float l = 0.f, v = 0.f;
        #pragma unroll
        for (int w = 0; w < K2THR / 64; ++w) { l += sl[w]; v += sv[w]; }
        ploss[blockIdx.x] = l;
        pev[blockIdx.x]   = v;
    }
}

// ---------------------------------------------------------------------------
// K3: final reduction of block partials -> scalar loss.
__global__ void cox_finalize(const float* __restrict__ ploss,
                             const float* __restrict__ pev,
                             float* __restrict__ out,
                             int nblocks) {
    const int tid = threadIdx.x;  // one wave
    float l = 0.f, v = 0.f;
    for (int k = tid; k < nblocks; k += 64) {
        l += ploss[k];
        v += pev[k];
    }
    #pragma unroll
    for (int off = 32; off > 0; off >>= 1) {
        l += __shfl_down(l, off, 64);
        v += __shfl_down(v, off, 64);
    }
    if (tid == 0) out[0] = l / fmaxf(v, 1.f);
}

// ---------------------------------------------------------------------------
extern "C" void kernel_launch(void* const* d_in, const int* in_sizes, int n_in,
                              void* d_out, int out_size, void* d_ws, size_t ws_size,
                              hipStream_t stream) {
    const float*  est = (const float*)d_in[0];
    const float2* tg  = (const float2*)d_in[1];   // target[N][2] = (t, event)
    float*        out = (float*)d_out;

    const int n = in_sizes[0];                    // 16384

    float* ws    = (float*)d_ws;
    float* ts    = ws;                            // [n]
    float* ss    = ws + n;                        // [n]
    int*   so    = (int*)(ws + 2 * n);            // [n]
    float* ploss = ws + 3 * n;                    // [K2NB]
    float* pev   = ploss + K2NB;                  // [K2NB]

    cox_sort<<<n / CSZ, CSZ, 0, stream>>>(tg, est, ts, ss, so);
    cox_search<<<K2NB, K2THR, 0, stream>>>(tg, est, ts, ss, so, ploss, pev);
    cox_finalize<<<1, 64, 0, stream>>>(ploss, pev, out, K2NB);
}